// Round 7
// baseline (183.500 us; speedup 1.0000x reference)
//
#include <hip/hip_runtime.h>
#include <math.h>

// RWKV WKV forward — chunked scan, NCC=256 chunks of LL=16, hierarchical prefix.
// State triple (aa, bb, pp) represents A = e^pp*aa, B = e^pp*bb; underlying
// recurrence is linear (A' = e^w A + e^k v) -> associative chunk combine.
//
// Round-7: same as round-6 plan (memory-level parallelism via pinned loads,
// 384-thread blocks), with ext_vector float2 to fix the compile errors.

#define NEG_INF (-1e38f)
#define NCC 256          // chunks per sequence
#define SCW 16           // chunks per superchunk
#define NSC (NCC / SCW)  // superchunks
#define LL  16           // timesteps per chunk (T=4096/NCC)

typedef float f2 __attribute__((ext_vector_type(2)));

__device__ __forceinline__ void wkv_step(float& aa, float& bb, float& pp,
                                         float wc, float kt, float vt) {
    float ww = wc + pp;
    float p  = fmaxf(ww, kt);
    float d  = ww - kt;
    float e  = __expf(-fabsf(d));
    float e1 = (d >= 0.f) ? 1.f : e;
    float e2 = (d >= 0.f) ? e   : 1.f;
    aa = e1 * aa + e2 * vt;
    bb = e1 * bb + e2;
    pp = p;
}

__device__ __forceinline__ float wkv_ostep(float aa, float bb, float pp,
                                           float uc, float kt, float vt) {
    float ww = uc + kt;
    float d  = pp - ww;
    float e  = __expf(-fabsf(d));
    float e1 = (d >= 0.f) ? 1.f : e;
    float e2 = (d >= 0.f) ? e   : 1.f;
    return __fdividef(e1 * aa + e2 * vt, e1 * bb + e2);
}

__device__ __forceinline__ void wkv_combine(float& aa, float& bb, float& pp,
                                            float dw, float la, float lb, float lp) {
    float ppd = pp + dw;
    float p   = fmaxf(ppd, lp);
    float e1  = __expf(ppd - p);
    float e2  = __expf(lp - p);
    aa = e1 * aa + e2 * la;
    bb = e1 * bb + e2 * lb;
    pp = p;
}

// Force-materialize both lanes of an ext-vector float2: the loads feeding it
// must have completed, and since all pins sit AFTER the whole load block,
// all loads are issued before any is consumed -> maximal loads in flight.
#define PIN2(vec) asm volatile("" :: "v"((vec).x), "v"((vec).y))

// ---------------------------------------------------------------------------
// Pass 1: per-(b, chunk) local summary. One block per (b,j); 384 threads,
// 2 adjacent channels each (float2).
__global__ __launch_bounds__(384, 8)
void wkv_pass1(const float* __restrict__ w,
               const float* __restrict__ kg,
               const float* __restrict__ vg,
               float* __restrict__ sa, float* __restrict__ sb,
               float* __restrict__ sp,
               int B, int T, int C) {
    const int b   = blockIdx.x / NCC;
    const int j   = blockIdx.x % NCC;
    const int tid = threadIdx.x;
    const int C2  = C >> 1;

    const f2* kp = (const f2*)(kg + ((size_t)b * T + (size_t)j * LL) * C) + tid;
    const f2* vp = (const f2*)(vg + ((size_t)b * T + (size_t)j * LL) * C) + tid;
    const f2  wc = ((const f2*)w)[tid];

    f2 kb[LL], vb[LL];
    #pragma unroll
    for (int t = 0; t < LL; ++t) { kb[t] = kp[t * C2]; vb[t] = vp[t * C2]; }
    #pragma unroll
    for (int t = 0; t < LL; ++t) { PIN2(kb[t]); PIN2(vb[t]); }

    float aa0 = 0.f, bb0 = 0.f, pp0 = NEG_INF;
    float aa1 = 0.f, bb1 = 0.f, pp1 = NEG_INF;
    #pragma unroll
    for (int t = 0; t < LL; ++t) {
        wkv_step(aa0, bb0, pp0, wc.x, kb[t].x, vb[t].x);
        wkv_step(aa1, bb1, pp1, wc.y, kb[t].y, vb[t].y);
    }

    const int base = j * (B * C) + b * C;
    f2 oa; oa.x = aa0; oa.y = aa1;
    f2 ob; ob.x = bb0; ob.y = bb1;
    f2 op; op.x = pp0; op.y = pp1;
    ((f2*)(sa + base))[tid] = oa;
    ((f2*)(sb + base))[tid] = ob;
    ((f2*)(sp + base))[tid] = op;
}

// ---------------------------------------------------------------------------
// Scan 2a: inclusive scan of SCW chunk summaries inside each superchunk,
// in place. One thread per (channel, superchunk). Load-all-then-store.
__global__ void wkv_scan_local(const float* __restrict__ w,
                               float* __restrict__ sa, float* __restrict__ sb,
                               float* __restrict__ sp,
                               int B, int C) {
    const int BC = B * C;
    int tid = blockIdx.x * blockDim.x + threadIdx.x;
    if (tid >= BC * NSC) return;
    const int bc = tid % BC;
    const int sc = tid / BC;
    const float wL = w[bc % C] * (float)LL;

    float la[SCW], lb[SCW], lp[SCW];
    #pragma unroll
    for (int i = 0; i < SCW; ++i) {
        const int idx = (sc * SCW + i) * BC + bc;
        la[i] = sa[idx]; lb[i] = sb[idx]; lp[i] = sp[idx];
    }
    float aa = 0.f, bb = 0.f, pp = NEG_INF;
    #pragma unroll
    for (int i = 0; i < SCW; ++i) {
        wkv_combine(aa, bb, pp, wL, la[i], lb[i], lp[i]);
        const int idx = (sc * SCW + i) * BC + bc;
        sa[idx] = aa; sb[idx] = bb; sp[idx] = pp;
    }
}

// ---------------------------------------------------------------------------
// Scan 2b: exclusive scan over superchunk totals (stored in each superchunk's
// last chunk slot); overwrite those slots with the superchunk carry-in E_sc.
__global__ void wkv_scan_super(const float* __restrict__ w,
                               float* __restrict__ sa, float* __restrict__ sb,
                               float* __restrict__ sp,
                               int B, int C) {
    const int BC = B * C;
    int bc = blockIdx.x * blockDim.x + threadIdx.x;
    if (bc >= BC) return;
    const float wSL = w[bc % C] * (float)(LL * SCW);

    float ta[NSC], tb[NSC], tp[NSC];
    #pragma unroll
    for (int sc = 0; sc < NSC; ++sc) {
        const int idx = (sc * SCW + (SCW - 1)) * BC + bc;
        ta[sc] = sa[idx]; tb[sc] = sb[idx]; tp[sc] = sp[idx];
    }
    float aa = 0.f, bb = 0.f, pp = NEG_INF;
    #pragma unroll
    for (int sc = 0; sc < NSC; ++sc) {
        const int idx = (sc * SCW + (SCW - 1)) * BC + bc;
        sa[idx] = aa; sb[idx] = bb; sp[idx] = pp;       // E_sc (exclusive)
        wkv_combine(aa, bb, pp, wSL, ta[sc], tb[sc], tp[sc]);
    }
}

// ---------------------------------------------------------------------------
// Pass 3: carry-in for chunk j = decay(E_sc, i*LL*w) (+) incl(j-1); replay
// chunk, emit y (nt stores: write-once data).
__global__ __launch_bounds__(384, 8)
void wkv_pass3(const float* __restrict__ w, const float* __restrict__ u,
               const float* __restrict__ kg, const float* __restrict__ vg,
               const float* __restrict__ sa, const float* __restrict__ sb,
               const float* __restrict__ sp,
               float* __restrict__ y,
               int B, int T, int C) {
    const int b   = blockIdx.x / NCC;
    const int j   = blockIdx.x % NCC;
    const int tid = threadIdx.x;
    const int C2  = C >> 1;
    const int BC  = B * C;

    const size_t rowbase = ((size_t)b * T + (size_t)j * LL) * C;
    const f2* kp = (const f2*)(kg + rowbase) + tid;
    const f2* vp = (const f2*)(vg + rowbase) + tid;
    f2*       yp = (f2*)(y + rowbase) + tid;
    const f2  wc = ((const f2*)w)[tid];
    const f2  uc = ((const f2*)u)[tid];

    f2 kb[LL], vb[LL];
    #pragma unroll
    for (int t = 0; t < LL; ++t) { kb[t] = kp[t * C2]; vb[t] = vp[t * C2]; }
    #pragma unroll
    for (int t = 0; t < LL; ++t) { PIN2(kb[t]); PIN2(vb[t]); }

    const int sc = j / SCW;
    const int i  = j % SCW;
    const int slot_last = (sc * SCW + (SCW - 1)) * BC + b * C;
    f2 Ea = ((const f2*)(sa + slot_last))[tid];
    f2 Eb = ((const f2*)(sb + slot_last))[tid];
    f2 Ep = ((const f2*)(sp + slot_last))[tid];

    float aa0, bb0, pp0, aa1, bb1, pp1;
    if (i == 0) {                       // block-uniform branch
        aa0 = Ea.x; bb0 = Eb.x; pp0 = Ep.x;
        aa1 = Ea.y; bb1 = Eb.y; pp1 = Ep.y;
    } else {
        const int prev = (j - 1) * BC + b * C;
        f2 la = ((const f2*)(sa + prev))[tid];
        f2 lb = ((const f2*)(sb + prev))[tid];
        f2 lp = ((const f2*)(sp + prev))[tid];
        const float steps = (float)(i * LL);
        aa0 = Ea.x; bb0 = Eb.x; pp0 = Ep.x;
        aa1 = Ea.y; bb1 = Eb.y; pp1 = Ep.y;
        wkv_combine(aa0, bb0, pp0, wc.x * steps, la.x, lb.x, lp.x);
        wkv_combine(aa1, bb1, pp1, wc.y * steps, la.y, lb.y, lp.y);
    }

    #pragma unroll
    for (int t = 0; t < LL; ++t) {
        f2 yo;
        yo.x = wkv_ostep(aa0, bb0, pp0, uc.x, kb[t].x, vb[t].x);
        yo.y = wkv_ostep(aa1, bb1, pp1, uc.y, kb[t].y, vb[t].y);
        __builtin_nontemporal_store(yo, yp + t * C2);
        wkv_step(aa0, bb0, pp0, wc.x, kb[t].x, vb[t].x);
        wkv_step(aa1, bb1, pp1, wc.y, kb[t].y, vb[t].y);
    }
}

// ---------------------------------------------------------------------------
extern "C" void kernel_launch(void* const* d_in, const int* in_sizes, int n_in,
                              void* d_out, int out_size, void* d_ws, size_t ws_size,
                              hipStream_t stream) {
    // inputs: 0=B 1=T 2=C 3=w 4=u 5=k 6=v
    const float* w = (const float*)d_in[3];
    const float* u = (const float*)d_in[4];
    const float* k = (const float*)d_in[5];
    const float* v = (const float*)d_in[6];
    float* y = (float*)d_out;

    const int C  = in_sizes[3];          // 768
    const int BT = in_sizes[5] / C;      // B*T
    const int T  = 4096;                 // fixed problem instance (T = NCC*LL)
    const int B  = BT / T;               // 8

    const int BC = B * C;
    const size_t total = (size_t)BC * NCC;
    float* sa = (float*)d_ws;
    float* sb = sa + total;
    float* sp = sb + total;

    const int nblk = B * NCC;            // 2048 blocks
    const int bthr = C / 2;              // 384 threads

    wkv_pass1<<<nblk, bthr, 0, stream>>>(w, k, v, sa, sb, sp, B, T, C);

    const int n2 = BC * NSC;
    wkv_scan_local<<<(n2 + 255) / 256, 256, 0, stream>>>(w, sa, sb, sp, B, C);
    wkv_scan_super<<<(BC + 255) / 256, 256, 0, stream>>>(w, sa, sb, sp, B, C);

    wkv_pass3<<<nblk, bthr, 0, stream>>>(w, u, k, v, sa, sb, sp, y, B, T, C);
}

// Round 8
// 108.087 us; speedup vs baseline: 1.6977x; 1.6977x over previous
//
#include <hip/hip_runtime.h>
#include <math.h>

// RWKV WKV forward — chunked scan, NCC=256 chunks of LL=16, hierarchical prefix.
// Round-8: (1) restore round-5 pass3 (f4 16B nt stores — 8B nt stores caused
// 2.5x HBM write amplification in round 7); (2) pass1 holds all 32 chunk loads
// in flight via a SINGLE asm volatile consuming all values (separate pins were
// legally interleaved with loads; one fat pin is unevadable -> VGPR >= 140).

#define NEG_INF (-1e38f)
#define NCC 256          // chunks per sequence
#define SCW 16           // chunks per superchunk
#define NSC (NCC / SCW)  // superchunks
#define LL  16           // timesteps per chunk (T=4096/NCC)

typedef float f4 __attribute__((ext_vector_type(4)));

__device__ __forceinline__ void wkv_step(float& aa, float& bb, float& pp,
                                         float wc, float kt, float vt) {
    float ww = wc + pp;
    float p  = fmaxf(ww, kt);
    float d  = ww - kt;
    float e  = __expf(-fabsf(d));
    float e1 = (d >= 0.f) ? 1.f : e;
    float e2 = (d >= 0.f) ? e   : 1.f;
    aa = e1 * aa + e2 * vt;
    bb = e1 * bb + e2;
    pp = p;
}

__device__ __forceinline__ float wkv_ostep(float aa, float bb, float pp,
                                           float uc, float kt, float vt) {
    float ww = uc + kt;
    float d  = pp - ww;
    float e  = __expf(-fabsf(d));
    float e1 = (d >= 0.f) ? 1.f : e;
    float e2 = (d >= 0.f) ? e   : 1.f;
    return __fdividef(e1 * aa + e2 * vt, e1 * bb + e2);
}

__device__ __forceinline__ void wkv_combine(float& aa, float& bb, float& pp,
                                            float dw, float la, float lb, float lp) {
    float ppd = pp + dw;
    float p   = fmaxf(ppd, lp);
    float e1  = __expf(ppd - p);
    float e2  = __expf(lp - p);
    aa = e1 * aa + e2 * la;
    bb = e1 * bb + e2 * lb;
    pp = p;
}

// One asm consuming ALL chunk data: every load must have issued (and completed)
// before this point; register allocator must keep all 32 f4 = 128 VGPRs live.
#define PIN_ALL(kb, vb) asm volatile("" ::                                   \
    "v"(kb[0]),  "v"(kb[1]),  "v"(kb[2]),  "v"(kb[3]),                       \
    "v"(kb[4]),  "v"(kb[5]),  "v"(kb[6]),  "v"(kb[7]),                       \
    "v"(kb[8]),  "v"(kb[9]),  "v"(kb[10]), "v"(kb[11]),                      \
    "v"(kb[12]), "v"(kb[13]), "v"(kb[14]), "v"(kb[15]),                      \
    "v"(vb[0]),  "v"(vb[1]),  "v"(vb[2]),  "v"(vb[3]),                       \
    "v"(vb[4]),  "v"(vb[5]),  "v"(vb[6]),  "v"(vb[7]),                       \
    "v"(vb[8]),  "v"(vb[9]),  "v"(vb[10]), "v"(vb[11]),                      \
    "v"(vb[12]), "v"(vb[13]), "v"(vb[14]), "v"(vb[15]))

// ---------------------------------------------------------------------------
// Pass 1: per-(b, chunk) local summary. One block per (b,j); 192 threads,
// 4 adjacent channels each (f4).
__global__ __launch_bounds__(192)
void wkv_pass1(const float* __restrict__ w,
               const float* __restrict__ kg,
               const float* __restrict__ vg,
               float* __restrict__ sa, float* __restrict__ sb,
               float* __restrict__ sp,
               int B, int T, int C) {
    const int b   = blockIdx.x / NCC;
    const int j   = blockIdx.x % NCC;
    const int tid = threadIdx.x;
    const int C4  = C >> 2;

    const f4* kp = (const f4*)(kg + ((size_t)b * T + (size_t)j * LL) * C) + tid;
    const f4* vp = (const f4*)(vg + ((size_t)b * T + (size_t)j * LL) * C) + tid;
    const f4  wc = ((const f4*)w)[tid];

    f4 kb[LL], vb[LL];
    #pragma unroll
    for (int t = 0; t < LL; ++t) { kb[t] = kp[t * C4]; vb[t] = vp[t * C4]; }
    PIN_ALL(kb, vb);

    float aa[4] = {0.f, 0.f, 0.f, 0.f};
    float bb[4] = {0.f, 0.f, 0.f, 0.f};
    float pp[4] = {NEG_INF, NEG_INF, NEG_INF, NEG_INF};
    #pragma unroll
    for (int t = 0; t < LL; ++t) {
        #pragma unroll
        for (int q = 0; q < 4; ++q) {
            float kt = kb[t][q], vt = vb[t][q];
            wkv_step(aa[q], bb[q], pp[q], wc[q], kt, vt);
        }
    }

    const int base = j * (B * C) + b * C;
    f4 oa = {aa[0], aa[1], aa[2], aa[3]};
    f4 ob = {bb[0], bb[1], bb[2], bb[3]};
    f4 op = {pp[0], pp[1], pp[2], pp[3]};
    ((f4*)(sa + base))[tid] = oa;
    ((f4*)(sb + base))[tid] = ob;
    ((f4*)(sp + base))[tid] = op;
}

// ---------------------------------------------------------------------------
// Scan 2a: inclusive scan of SCW chunk summaries inside each superchunk,
// in place. One thread per (channel, superchunk). Load-all-then-store.
__global__ void wkv_scan_local(const float* __restrict__ w,
                               float* __restrict__ sa, float* __restrict__ sb,
                               float* __restrict__ sp,
                               int B, int C) {
    const int BC = B * C;
    int tid = blockIdx.x * blockDim.x + threadIdx.x;
    if (tid >= BC * NSC) return;
    const int bc = tid % BC;
    const int sc = tid / BC;
    const float wL = w[bc % C] * (float)LL;

    float la[SCW], lb[SCW], lp[SCW];
    #pragma unroll
    for (int i = 0; i < SCW; ++i) {
        const int idx = (sc * SCW + i) * BC + bc;
        la[i] = sa[idx]; lb[i] = sb[idx]; lp[i] = sp[idx];
    }
    float aa = 0.f, bb = 0.f, pp = NEG_INF;
    #pragma unroll
    for (int i = 0; i < SCW; ++i) {
        wkv_combine(aa, bb, pp, wL, la[i], lb[i], lp[i]);
        const int idx = (sc * SCW + i) * BC + bc;
        sa[idx] = aa; sb[idx] = bb; sp[idx] = pp;
    }
}

// ---------------------------------------------------------------------------
// Scan 2b: exclusive scan over superchunk totals (in each superchunk's last
// chunk slot); overwrite those slots with the superchunk carry-in E_sc.
__global__ void wkv_scan_super(const float* __restrict__ w,
                               float* __restrict__ sa, float* __restrict__ sb,
                               float* __restrict__ sp,
                               int B, int C) {
    const int BC = B * C;
    int bc = blockIdx.x * blockDim.x + threadIdx.x;
    if (bc >= BC) return;
    const float wSL = w[bc % C] * (float)(LL * SCW);

    float ta[NSC], tb[NSC], tp[NSC];
    #pragma unroll
    for (int sc = 0; sc < NSC; ++sc) {
        const int idx = (sc * SCW + (SCW - 1)) * BC + bc;
        ta[sc] = sa[idx]; tb[sc] = sb[idx]; tp[sc] = sp[idx];
    }
    float aa = 0.f, bb = 0.f, pp = NEG_INF;
    #pragma unroll
    for (int sc = 0; sc < NSC; ++sc) {
        const int idx = (sc * SCW + (SCW - 1)) * BC + bc;
        sa[idx] = aa; sb[idx] = bb; sp[idx] = pp;       // E_sc (exclusive)
        wkv_combine(aa, bb, pp, wSL, ta[sc], tb[sc], tp[sc]);
    }
}

// ---------------------------------------------------------------------------
// Pass 3: carry-in for chunk j = decay(E_sc, i*LL*w) (+) incl(j-1); replay
// chunk, emit y with 16-byte nt stores (8B nt stores write-amplify 2.5x).
__global__ __launch_bounds__(192)
void wkv_pass3(const float* __restrict__ w, const float* __restrict__ u,
               const float* __restrict__ kg, const float* __restrict__ vg,
               const float* __restrict__ sa, const float* __restrict__ sb,
               const float* __restrict__ sp,
               float* __restrict__ y,
               int B, int T, int C) {
    const int b   = blockIdx.x / NCC;
    const int j   = blockIdx.x % NCC;
    const int tid = threadIdx.x;
    const int C4  = C >> 2;
    const int BC  = B * C;

    const size_t rowbase = ((size_t)b * T + (size_t)j * LL) * C;
    const f4* kp = (const f4*)(kg + rowbase) + tid;
    const f4* vp = (const f4*)(vg + rowbase) + tid;
    f4*       yp = (f4*)(y + rowbase) + tid;
    const f4  wc = ((const f4*)w)[tid];
    const f4  uc = ((const f4*)u)[tid];

    f4 kb[LL], vb[LL];
    #pragma unroll
    for (int t = 0; t < LL; ++t) { kb[t] = kp[t * C4]; vb[t] = vp[t * C4]; }
    PIN_ALL(kb, vb);

    const int sc = j / SCW;
    const int i  = j % SCW;
    const int slot_last = (sc * SCW + (SCW - 1)) * BC + b * C;
    f4 Ea = ((const f4*)(sa + slot_last))[tid];
    f4 Eb = ((const f4*)(sb + slot_last))[tid];
    f4 Ep = ((const f4*)(sp + slot_last))[tid];

    float aa[4], bb[4], pp[4];
    if (i == 0) {                       // block-uniform branch
        #pragma unroll
        for (int q = 0; q < 4; ++q) { aa[q] = Ea[q]; bb[q] = Eb[q]; pp[q] = Ep[q]; }
    } else {
        const int prev = (j - 1) * BC + b * C;
        f4 la = ((const f4*)(sa + prev))[tid];
        f4 lb = ((const f4*)(sb + prev))[tid];
        f4 lp = ((const f4*)(sp + prev))[tid];
        const float steps = (float)(i * LL);
        #pragma unroll
        for (int q = 0; q < 4; ++q) {
            float a = Ea[q], bq = Eb[q], p = Ep[q];
            wkv_combine(a, bq, p, wc[q] * steps, la[q], lb[q], lp[q]);
            aa[q] = a; bb[q] = bq; pp[q] = p;
        }
    }

    #pragma unroll
    for (int t = 0; t < LL; ++t) {
        f4 yo;
        #pragma unroll
        for (int q = 0; q < 4; ++q) {
            float kt = kb[t][q], vt = vb[t][q];
            yo[q] = wkv_ostep(aa[q], bb[q], pp[q], uc[q], kt, vt);
            wkv_step(aa[q], bb[q], pp[q], wc[q], kt, vt);
        }
        __builtin_nontemporal_store(yo, yp + t * C4);
    }
}

// ---------------------------------------------------------------------------
extern "C" void kernel_launch(void* const* d_in, const int* in_sizes, int n_in,
                              void* d_out, int out_size, void* d_ws, size_t ws_size,
                              hipStream_t stream) {
    // inputs: 0=B 1=T 2=C 3=w 4=u 5=k 6=v
    const float* w = (const float*)d_in[3];
    const float* u = (const float*)d_in[4];
    const float* k = (const float*)d_in[5];
    const float* v = (const float*)d_in[6];
    float* y = (float*)d_out;

    const int C  = in_sizes[3];          // 768
    const int BT = in_sizes[5] / C;      // B*T
    const int T  = 4096;                 // fixed problem instance (T = NCC*LL)
    const int B  = BT / T;               // 8

    const int BC = B * C;
    const size_t total = (size_t)BC * NCC;
    float* sa = (float*)d_ws;
    float* sb = sa + total;
    float* sp = sb + total;

    const int nblk = B * NCC;            // 2048 blocks
    const int bthr = C / 4;              // 192 threads, 4 channels each

    wkv_pass1<<<nblk, bthr, 0, stream>>>(w, k, v, sa, sb, sp, B, T, C);

    const int n2 = BC * NSC;
    wkv_scan_local<<<(n2 + 255) / 256, 256, 0, stream>>>(w, sa, sb, sp, B, C);
    wkv_scan_super<<<(BC + 255) / 256, 256, 0, stream>>>(w, sa, sb, sp, B, C);

    wkv_pass3<<<nblk, bthr, 0, stream>>>(w, u, k, v, sa, sb, sp, y, B, T, C);
}

// Round 9
// 105.788 us; speedup vs baseline: 1.7346x; 1.0217x over previous
//
#include <hip/hip_runtime.h>
#include <math.h>

// RWKV WKV forward — chunked scan, NCC=256 chunks of LL=16, hierarchical prefix.
// Round-9: pass1 loads issued as raw inline-asm global_load_dwordx4 (volatile,
// mutually ordered, no compiler-inserted waits) + single s_waitcnt vmcnt(0) +
// sched_barrier(0). This is the only mechanism hipcc cannot defeat (rounds
// 1/2/5/8 all collapsed to ~1-2 loads in flight): 32 KB/wave guaranteed in
// flight. pass3/scans unchanged from round 8 (~28 us combined).

#define NEG_INF (-1e38f)
#define NCC 256          // chunks per sequence
#define SCW 16           // chunks per superchunk
#define NSC (NCC / SCW)  // superchunks
#define LL  16           // timesteps per chunk (T=4096/NCC)

typedef float f4 __attribute__((ext_vector_type(4)));

__device__ __forceinline__ void wkv_step(float& aa, float& bb, float& pp,
                                         float wc, float kt, float vt) {
    float ww = wc + pp;
    float p  = fmaxf(ww, kt);
    float d  = ww - kt;
    float e  = __expf(-fabsf(d));
    float e1 = (d >= 0.f) ? 1.f : e;
    float e2 = (d >= 0.f) ? e   : 1.f;
    aa = e1 * aa + e2 * vt;
    bb = e1 * bb + e2;
    pp = p;
}

__device__ __forceinline__ float wkv_ostep(float aa, float bb, float pp,
                                           float uc, float kt, float vt) {
    float ww = uc + kt;
    float d  = pp - ww;
    float e  = __expf(-fabsf(d));
    float e1 = (d >= 0.f) ? 1.f : e;
    float e2 = (d >= 0.f) ? e   : 1.f;
    return __fdividef(e1 * aa + e2 * vt, e1 * bb + e2);
}

__device__ __forceinline__ void wkv_combine(float& aa, float& bb, float& pp,
                                            float dw, float la, float lb, float lp) {
    float ppd = pp + dw;
    float p   = fmaxf(ppd, lp);
    float e1  = __expf(ppd - p);
    float e2  = __expf(lp - p);
    aa = e1 * aa + e2 * la;
    bb = e1 * bb + e2 * lb;
    pp = p;
}

// ---------------------------------------------------------------------------
// Pass 1: per-(b, chunk) local summary. One block per (b,j); 192 threads,
// 4 adjacent channels each. Loads issued via inline asm -> 32 KB/wave in
// flight, drained by one vmcnt(0).
__global__ __launch_bounds__(192)
void wkv_pass1(const float* __restrict__ w,
               const float* __restrict__ kg,
               const float* __restrict__ vg,
               float* __restrict__ sa, float* __restrict__ sb,
               float* __restrict__ sp,
               int B, int T, int C) {
    const int b   = blockIdx.x / NCC;
    const int j   = blockIdx.x % NCC;
    const int tid = threadIdx.x;

    const float* kbase = kg + ((size_t)b * T + (size_t)j * LL) * C + 4 * tid;
    const float* vbase = vg + ((size_t)b * T + (size_t)j * LL) * C + 4 * tid;
    const f4 wc = *(const f4*)(w + 4 * tid);

    f4 kb[LL], vb[LL];
    #pragma unroll
    for (int t = 0; t < LL; ++t) {
        asm volatile("global_load_dwordx4 %0, %1, off"
                     : "=v"(kb[t]) : "v"(kbase + (size_t)t * C));
        asm volatile("global_load_dwordx4 %0, %1, off"
                     : "=v"(vb[t]) : "v"(vbase + (size_t)t * C));
    }
    asm volatile("s_waitcnt vmcnt(0)" ::: "memory");
    __builtin_amdgcn_sched_barrier(0);

    float aa[4] = {0.f, 0.f, 0.f, 0.f};
    float bb[4] = {0.f, 0.f, 0.f, 0.f};
    float pp[4] = {NEG_INF, NEG_INF, NEG_INF, NEG_INF};
    #pragma unroll
    for (int t = 0; t < LL; ++t) {
        #pragma unroll
        for (int q = 0; q < 4; ++q) {
            float kt = kb[t][q], vt = vb[t][q];
            wkv_step(aa[q], bb[q], pp[q], wc[q], kt, vt);
        }
    }

    const int base = j * (B * C) + b * C;
    f4 oa = {aa[0], aa[1], aa[2], aa[3]};
    f4 ob = {bb[0], bb[1], bb[2], bb[3]};
    f4 op = {pp[0], pp[1], pp[2], pp[3]};
    ((f4*)(sa + base))[tid] = oa;
    ((f4*)(sb + base))[tid] = ob;
    ((f4*)(sp + base))[tid] = op;
}

// ---------------------------------------------------------------------------
// Scan 2a: inclusive scan of SCW chunk summaries inside each superchunk,
// in place. One thread per (channel, superchunk). Load-all-then-store.
__global__ void wkv_scan_local(const float* __restrict__ w,
                               float* __restrict__ sa, float* __restrict__ sb,
                               float* __restrict__ sp,
                               int B, int C) {
    const int BC = B * C;
    int tid = blockIdx.x * blockDim.x + threadIdx.x;
    if (tid >= BC * NSC) return;
    const int bc = tid % BC;
    const int sc = tid / BC;
    const float wL = w[bc % C] * (float)LL;

    float la[SCW], lb[SCW], lp[SCW];
    #pragma unroll
    for (int i = 0; i < SCW; ++i) {
        const int idx = (sc * SCW + i) * BC + bc;
        la[i] = sa[idx]; lb[i] = sb[idx]; lp[i] = sp[idx];
    }
    float aa = 0.f, bb = 0.f, pp = NEG_INF;
    #pragma unroll
    for (int i = 0; i < SCW; ++i) {
        wkv_combine(aa, bb, pp, wL, la[i], lb[i], lp[i]);
        const int idx = (sc * SCW + i) * BC + bc;
        sa[idx] = aa; sb[idx] = bb; sp[idx] = pp;
    }
}

// ---------------------------------------------------------------------------
// Scan 2b: exclusive scan over superchunk totals (in each superchunk's last
// chunk slot); overwrite those slots with the superchunk carry-in E_sc.
__global__ void wkv_scan_super(const float* __restrict__ w,
                               float* __restrict__ sa, float* __restrict__ sb,
                               float* __restrict__ sp,
                               int B, int C) {
    const int BC = B * C;
    int bc = blockIdx.x * blockDim.x + threadIdx.x;
    if (bc >= BC) return;
    const float wSL = w[bc % C] * (float)(LL * SCW);

    float ta[NSC], tb[NSC], tp[NSC];
    #pragma unroll
    for (int sc = 0; sc < NSC; ++sc) {
        const int idx = (sc * SCW + (SCW - 1)) * BC + bc;
        ta[sc] = sa[idx]; tb[sc] = sb[idx]; tp[sc] = sp[idx];
    }
    float aa = 0.f, bb = 0.f, pp = NEG_INF;
    #pragma unroll
    for (int sc = 0; sc < NSC; ++sc) {
        const int idx = (sc * SCW + (SCW - 1)) * BC + bc;
        sa[idx] = aa; sb[idx] = bb; sp[idx] = pp;       // E_sc (exclusive)
        wkv_combine(aa, bb, pp, wSL, ta[sc], tb[sc], tp[sc]);
    }
}

// ---------------------------------------------------------------------------
// Pass 3: carry-in for chunk j = decay(E_sc, i*LL*w) (+) incl(j-1); replay
// chunk, emit y with 16-byte nt stores (8B nt stores write-amplify 2.5x).
__global__ __launch_bounds__(192)
void wkv_pass3(const float* __restrict__ w, const float* __restrict__ u,
               const float* __restrict__ kg, const float* __restrict__ vg,
               const float* __restrict__ sa, const float* __restrict__ sb,
               const float* __restrict__ sp,
               float* __restrict__ y,
               int B, int T, int C) {
    const int b   = blockIdx.x / NCC;
    const int j   = blockIdx.x % NCC;
    const int tid = threadIdx.x;
    const int C4  = C >> 2;
    const int BC  = B * C;

    const size_t rowbase = ((size_t)b * T + (size_t)j * LL) * C;
    const f4* kp = (const f4*)(kg + rowbase) + tid;
    const f4* vp = (const f4*)(vg + rowbase) + tid;
    f4*       yp = (f4*)(y + rowbase) + tid;
    const f4  wc = ((const f4*)w)[tid];
    const f4  uc = ((const f4*)u)[tid];

    f4 kb[LL], vb[LL];
    #pragma unroll
    for (int t = 0; t < LL; ++t) { kb[t] = kp[t * C4]; vb[t] = vp[t * C4]; }

    const int sc = j / SCW;
    const int i  = j % SCW;
    const int slot_last = (sc * SCW + (SCW - 1)) * BC + b * C;
    f4 Ea = ((const f4*)(sa + slot_last))[tid];
    f4 Eb = ((const f4*)(sb + slot_last))[tid];
    f4 Ep = ((const f4*)(sp + slot_last))[tid];

    float aa[4], bb[4], pp[4];
    if (i == 0) {                       // block-uniform branch
        #pragma unroll
        for (int q = 0; q < 4; ++q) { aa[q] = Ea[q]; bb[q] = Eb[q]; pp[q] = Ep[q]; }
    } else {
        const int prev = (j - 1) * BC + b * C;
        f4 la = ((const f4*)(sa + prev))[tid];
        f4 lb = ((const f4*)(sb + prev))[tid];
        f4 lp = ((const f4*)(sp + prev))[tid];
        const float steps = (float)(i * LL);
        #pragma unroll
        for (int q = 0; q < 4; ++q) {
            float a = Ea[q], bq = Eb[q], p = Ep[q];
            wkv_combine(a, bq, p, wc[q] * steps, la[q], lb[q], lp[q]);
            aa[q] = a; bb[q] = bq; pp[q] = p;
        }
    }

    #pragma unroll
    for (int t = 0; t < LL; ++t) {
        f4 yo;
        #pragma unroll
        for (int q = 0; q < 4; ++q) {
            float kt = kb[t][q], vt = vb[t][q];
            yo[q] = wkv_ostep(aa[q], bb[q], pp[q], uc[q], kt, vt);
            wkv_step(aa[q], bb[q], pp[q], wc[q], kt, vt);
        }
        __builtin_nontemporal_store(yo, yp + t * C4);
    }
}

// ---------------------------------------------------------------------------
extern "C" void kernel_launch(void* const* d_in, const int* in_sizes, int n_in,
                              void* d_out, int out_size, void* d_ws, size_t ws_size,
                              hipStream_t stream) {
    // inputs: 0=B 1=T 2=C 3=w 4=u 5=k 6=v
    const float* w = (const float*)d_in[3];
    const float* u = (const float*)d_in[4];
    const float* k = (const float*)d_in[5];
    const float* v = (const float*)d_in[6];
    float* y = (float*)d_out;

    const int C  = in_sizes[3];          // 768
    const int BT = in_sizes[5] / C;      // B*T
    const int T  = 4096;                 // fixed problem instance (T = NCC*LL)
    const int B  = BT / T;               // 8

    const int BC = B * C;
    const size_t total = (size_t)BC * NCC;
    float* sa = (float*)d_ws;
    float* sb = sa + total;
    float* sp = sb + total;

    const int nblk = B * NCC;            // 2048 blocks
    const int bthr = C / 4;              // 192 threads, 4 channels each

    wkv_pass1<<<nblk, bthr, 0, stream>>>(w, k, v, sa, sb, sp, B, T, C);

    const int n2 = BC * NSC;
    wkv_scan_local<<<(n2 + 255) / 256, 256, 0, stream>>>(w, sa, sb, sp, B, C);
    wkv_scan_super<<<(BC + 255) / 256, 256, 0, stream>>>(w, sa, sb, sp, B, C);

    wkv_pass3<<<nblk, bthr, 0, stream>>>(w, u, k, v, sa, sb, sp, y, B, T, C);
}